// Round 14
// baseline (250.607 us; speedup 1.0000x reference)
//
#include <hip/hip_runtime.h>
#include <stdint.h>

// MLA bf16-MFMA pipeline R19:
// B=2, N=2048, D=1024, L=512, H=16, Dh=64.
// GEMMs: reverted to R16 exactly (BK=128 single-buffer; BN=128 main/k2v2,
// BN=64 out/wGEMM) after R17 (dbuf) and R18 (BN=64 everywhere) both regressed.
// Flash v7 = v6 structure SPLIT-KV: each block handles HALF the kv range
// (16 tiles of 64), grid 512->1024 = 3 blocks/CU (LDS 48KB, cap 3.33) ->
// waves/CU 8->12 on a dependency-latency-bound kernel (no pipe >42%).
// Partial per half: normalized O + (l, m) per (row,head); merge kernel
// combines with w_i = l_i*2^(m_i-m*). m_run is 16-lane-group uniform by
// construction (only updated in the reduced rare path).
// Launches: prep, wGEMM, mainGEMM, k2v2(OUTVT), flash, merge, out = 7.
// MODEL NOTES (verified): SQ_LDS_BANK_CONFLICT = 4 x ds_read_b128 (b128 tax);
// GEMM: BK amortization proven (-21.7us), dbuf null, BN=64 regression;
// flash: not HBM-bound, not stall-bound; limiter = per-wave dep latency.

typedef __attribute__((ext_vector_type(8))) __bf16 bf16x8;
typedef __attribute__((ext_vector_type(4))) float f32x4;

__device__ inline unsigned short f2bfu(float f) {
    __bf16 b = (__bf16)f;
    return __builtin_bit_cast(unsigned short, b);
}

__device__ inline float bfu2f(unsigned short u) {
    unsigned int x = ((unsigned int)u) << 16;
    return __builtin_bit_cast(float, x);
}

__device__ inline float exp2_fast(float f) {
    return __builtin_amdgcn_exp2f(f);   // raw v_exp_f32
}

__device__ inline void load_lds16(const void* g, void* l) {
    __builtin_amdgcn_global_load_lds(
        (const __attribute__((address_space(1))) uint32_t*)g,
        (__attribute__((address_space(3))) uint32_t*)l, 16, 0, 0);
}

__device__ inline f32x4 mfma_bf16(bf16x8 a, bf16x8 b, f32x4 c) {
    return __builtin_amdgcn_mfma_f32_16x16x32_bf16(a, b, c, 0, 0, 0);
}

// ---------------- merged prep kernel ----------------
// blocks [0,4096):      cvt x f32->bf16 (4 elems/thread)
// blocks [4096,6144):   cvt Wkv f32->bf16 (layout kept, [1024][2048])
// blocks [6144,7168):   weight transposes f32 [R][C] -> bf16 [C][R]*sc
__global__ __launch_bounds__(256) void prep_kernel(
    const float* __restrict__ x, unsigned short* __restrict__ xb,
    const float* __restrict__ Wkv, unsigned short* __restrict__ Wkvb,
    const float* __restrict__ Wq,  const float* __restrict__ Wo,
    const float* __restrict__ Wk1, const float* __restrict__ Wv1,
    const float* __restrict__ Wk2, const float* __restrict__ Wv2,
    unsigned short* __restrict__ WqkvT, unsigned short* __restrict__ WoT,
    unsigned short* __restrict__ Wk1T,  unsigned short* __restrict__ Wv1T,
    unsigned short* __restrict__ Wk2T,  unsigned short* __restrict__ Wv2T,
    float qscale)
{
    __shared__ float tile[64][65];
    int id = blockIdx.x;
    int t = threadIdx.x;

    if (id < 6144) {   // ---- elementwise cvt (x, Wkv) ----
        const float* s = (id < 4096) ? x : Wkv;
        unsigned short* d = (id < 4096) ? xb : Wkvb;
        int base = (id < 4096) ? id : (id - 4096);
        int i = (base * 256 + t) * 4;
        float4 v = *(const float4*)&s[i];
        ushort4 o;
        o.x = f2bfu(v.x); o.y = f2bfu(v.y); o.z = f2bfu(v.z); o.w = f2bfu(v.w);
        *(ushort4*)&d[i] = o;
        return;
    }

    // ---- transposes ----
    int r = id - 6144;
    const float* src; unsigned short* dst; int R, C; float sc; int bx, by;
    if (r < 512) {          // Wq / Wo : 16 x 16 x 2
        int z = r >> 8; int rr = r & 255; bx = rr & 15; by = rr >> 4;
        src = z ? Wo : Wq; dst = z ? WoT : WqkvT;
        R = 1024; C = 1024; sc = z ? 1.0f : qscale;
    } else if (r < 768) {   // Wk1 / Wv1 : 8 x 16 x 2
        int rr = r - 512; int z = rr >> 7; rr &= 127; bx = rr & 7; by = rr >> 3;
        src = z ? Wv1 : Wk1; dst = z ? Wv1T : Wk1T;
        R = 1024; C = 512; sc = 1.0f;
    } else {                // Wk2 / Wv2 : 16 x 8 x 2
        int rr = r - 768; int z = rr >> 7; rr &= 127; bx = rr & 15; by = rr >> 4;
        src = z ? Wv2 : Wk2; dst = z ? Wv2T : Wk2T;
        R = 512; C = 1024; sc = 1.0f;
    }

    int c0 = bx * 64, r0 = by * 64;
    int col = t & 63, rr4 = t >> 6;
#pragma unroll
    for (int i = 0; i < 16; ++i)
        tile[rr4 + i * 4][col] = src[(size_t)(r0 + rr4 + i * 4) * C + c0 + col];
    __syncthreads();
#pragma unroll
    for (int i = 0; i < 16; ++i) {
        int r2 = rr4 + i * 4;
        dst[(size_t)(c0 + r2) * R + r0 + col] = f2bfu(tile[col][r2] * sc);
    }
}

// ---------------- bf16 MFMA GEMM (m97 structure, BK=128, BN templated) -----
// C[M][N] = A[M][K] @ Bt[N][K]^T (+bias)(relu). 128xBN tile, BK=128 as four
// [rows][32] sub-chunks. grid (N/BN, M/128, nz), block 256. K % 128 == 0.
// relu: 0=none, 1=all, 2=only columns >= 1024.
// OUTVT: on the z=1 path, write C transposed into C1 as
// vt[(b*1024 + col) * 2048 + (m & 2047)] (b = m >> 11), b64-packed over r.
template<int BN, bool OUTVT = false>
__global__ __launch_bounds__(256) void gemm_bf16_kernel(
    const unsigned short* __restrict__ A0, const unsigned short* __restrict__ A1,
    const unsigned short* __restrict__ B0, const unsigned short* __restrict__ B1,
    void* __restrict__ C0, void* __restrict__ C1,
    int lda, int ldb, int ldc, int K,
    const float* __restrict__ bias, int relu, int out_f32)
{
    const unsigned short* A = blockIdx.z ? A1 : A0;
    const unsigned short* Bt = blockIdx.z ? B1 : B0;
    void* C = blockIdx.z ? C1 : C0;

    constexpr int NI = BN / 32;        // N-frags per wave
    constexpr int AH = 128 * 32;       // halfwords per A sub-chunk
    constexpr int BH = BN * 32;        // halfwords per B sub-chunk
    __shared__ unsigned short Als[4 * AH];
    __shared__ unsigned short Bls[4 * BH];
    int t = threadIdx.x;
    int lane = t & 63, w = t >> 6;
    int n0 = blockIdx.x * BN, m0 = blockIdx.y * 128;
    int wm = (w & 1) * 64, wn = (w >> 1) * (BN / 2);
    int lrow = lane & 15, quad = lane >> 4;

    f32x4 acc[4][NI];
    f32x4 z = {0.f, 0.f, 0.f, 0.f};
#pragma unroll
    for (int i = 0; i < 4; ++i)
#pragma unroll
        for (int j = 0; j < NI; ++j) acc[i][j] = z;

    int c0 = t, c1 = t + 256;
    const unsigned short* ag0 = A + (size_t)(m0 + (c0 >> 2)) * lda + (c0 & 3) * 8;
    const unsigned short* ag1 = A + (size_t)(m0 + (c1 >> 2)) * lda + (c1 & 3) * 8;
    const unsigned short* bg0 = Bt + (size_t)(n0 + (c0 >> 2)) * ldb + (c0 & 3) * 8;
    const unsigned short* bg1 = Bt + (size_t)(n0 + ((c1 >> 2) & (BN - 1))) * ldb + (c1 & 3) * 8;

    for (int k0 = 0; k0 < K; k0 += 128) {
        __syncthreads();
        // four 32-wide sub-chunks, one barrier for all
#pragma unroll
        for (int h = 0; h < 4; ++h) {
            load_lds16(ag0 + k0 + h * 32, &Als[h * AH + c0 * 8]);
            load_lds16(ag1 + k0 + h * 32, &Als[h * AH + c1 * 8]);
            load_lds16(bg0 + k0 + h * 32, &Bls[h * BH + c0 * 8]);
            if constexpr (BN == 128)
                load_lds16(bg1 + k0 + h * 32, &Bls[h * BH + c1 * 8]);
        }
        __syncthreads();

#pragma unroll
        for (int kk = 0; kk < 4; ++kk) {
            bf16x8 af[4], bfr[NI];
#pragma unroll
            for (int mi = 0; mi < 4; ++mi)
                af[mi] = *(const bf16x8*)&Als[kk * AH + (wm + mi * 16 + lrow) * 32 + quad * 8];
#pragma unroll
            for (int ni = 0; ni < NI; ++ni)
                bfr[ni] = *(const bf16x8*)&Bls[kk * BH + (wn + ni * 16 + lrow) * 32 + quad * 8];
#pragma unroll
            for (int mi = 0; mi < 4; ++mi)
#pragma unroll
                for (int ni = 0; ni < NI; ++ni)
                    acc[mi][ni] = mfma_bf16(af[mi], bfr[ni], acc[mi][ni]);
        }
    }

    if (OUTVT && blockIdx.z) {
        // transposed store: vt row = b*1024 + col, col index = n' (seq within batch)
        int bb = m0 >> 11;
        int npb = (m0 & 2047) + wm;
        unsigned short* vt = (unsigned short*)C;
#pragma unroll
        for (int mi = 0; mi < 4; ++mi)
#pragma unroll
            for (int ni = 0; ni < NI; ++ni) {
                int col = n0 + wn + ni * 16 + lrow;
                int np = npb + mi * 16 + quad * 4;
                ushort4 o;
                o.x = f2bfu(acc[mi][ni][0]);
                o.y = f2bfu(acc[mi][ni][1]);
                o.z = f2bfu(acc[mi][ni][2]);
                o.w = f2bfu(acc[mi][ni][3]);
                *(ushort4*)&vt[(size_t)(bb * 1024 + col) * 2048 + np] = o;
            }
        return;
    }

#pragma unroll
    for (int mi = 0; mi < 4; ++mi)
#pragma unroll
        for (int ni = 0; ni < NI; ++ni)
#pragma unroll
            for (int r = 0; r < 4; ++r) {
                int row = m0 + wm + mi * 16 + quad * 4 + r;
                int col = n0 + wn + ni * 16 + lrow;
                float v = acc[mi][ni][r];
                if (bias) v += bias[col];
                if (relu == 1 || (relu == 2 && col >= 1024)) v = fmaxf(v, 0.0f);
                if (out_f32) ((float*)C)[(size_t)row * ldc + col] = v;
                else ((unsigned short*)C)[(size_t)row * ldc + col] = f2bfu(v);
            }
}

// ---------------- MFMA flash attention v7 (split-KV) ----------------
// Q (ldq, scaled by 0.125*log2e), K (ldk): head-interleaved; Vt [32*64][2048].
// grid 1024 1D (XCD-swizzled), block 256 (4 waves). Block handles kv half
// kvh (16 tiles of 64). Wave w owns Q rows w*32..+31 as 2 q-subtiles of 16.
// K/V double-buffered; stage(t+1) before compute(t); ONE barrier per tile.
// Softmax log2-domain, defer-max THR=8, lane-partial l. P per-wave per-qb
// [16][64] hw, XOR swizzle byte^=(row&7)<<4.
// Output: Oh[kvh][row][1024] normalized + lm[kvh][row][h] = (l, m).
__global__ __launch_bounds__(256, 3) void flash_mfma_kernel(
    const unsigned short* __restrict__ Q, int ldq,
    const unsigned short* __restrict__ K, int ldk,
    const unsigned short* __restrict__ Vt,
    unsigned short* __restrict__ Oh, float* __restrict__ lm)
{
    __shared__ __align__(16) unsigned short Kls[2][2 * 64 * 32]; // 8KB ea
    __shared__ __align__(16) unsigned short Vls[2][2 * 64 * 32]; // 8KB ea
    __shared__ __align__(16) unsigned short Pls[4][2][16 * 64];  // swz 16KB

    // XCD swizzle: 1024 = 8 XCDs x 128; each XCD gets 4 consecutive bh.
    int pbid = blockIdx.x;
    int lbid = (pbid >> 3) + (pbid & 7) * 128;
    int bh = lbid >> 5;
    int s5 = lbid & 31;
    int kvh = s5 & 1;                  // kv half
    int q0 = (s5 >> 1) * 128;
    int b = bh >> 4, h = bh & 15;
    int t = threadIdx.x;
    int lane = t & 63, w = t >> 6;
    int lrow = lane & 15, quad = lane >> 4;
    int kt0 = kvh * 1024;

    // Q fragments: 2 q-subtiles x 2 k-halves (A-layout: row=lrow, k=quad*8)
    bf16x8 qf[2][2];
#pragma unroll
    for (int qb = 0; qb < 2; ++qb) {
        const unsigned short* qrow =
            Q + (size_t)(b * 2048 + q0 + w * 32 + qb * 16 + lrow) * ldq + h * 64;
        qf[qb][0] = *(const bf16x8*)&qrow[quad * 8];
        qf[qb][1] = *(const bf16x8*)&qrow[32 + quad * 8];
    }

    f32x4 z = {0.f, 0.f, 0.f, 0.f};
    f32x4 acco[2][4];
    float m_run[2][4], l_run[2][4];
#pragma unroll
    for (int qb = 0; qb < 2; ++qb)
#pragma unroll
        for (int r = 0; r < 4; ++r) {
            acco[qb][r] = z;
            m_run[qb][r] = -1e30f;
            l_run[qb][r] = 0.f;   // lane-partial sum
        }

    // staging: thread t covers row t>>2 (0..63), segment (t&3)*8
    int row4 = t >> 2;
    int seg = (t & 3) * 8;
    const unsigned short* kg = K + (size_t)(b * 2048 + row4) * ldk + h * 64 + seg;
    const unsigned short* vg = Vt + (size_t)(bh * 64 + row4) * 2048 + seg;

    char* pb[2] = { (char*)&Pls[w][0][0], (char*)&Pls[w][1][0] };

    // prologue: stage tile kt0 -> buf 0
    load_lds16(kg + (size_t)kt0 * ldk,      &Kls[0][t * 8]);
    load_lds16(kg + (size_t)kt0 * ldk + 32, &Kls[0][2048 + t * 8]);
    load_lds16(vg + kt0,      &Vls[0][t * 8]);
    load_lds16(vg + kt0 + 32, &Vls[0][2048 + t * 8]);
    __syncthreads();

    int cur = 0;
    for (int kt = kt0; kt < kt0 + 1024; kt += 64) {
        // issue next-tile stage into buf cur^1; latency hides under compute
        if (kt + 64 < kt0 + 1024) {
            const unsigned short* kgk = kg + (size_t)(kt + 64) * ldk;
            const unsigned short* vgk = vg + kt + 64;
            int nb = cur ^ 1;
            load_lds16(kgk,      &Kls[nb][t * 8]);
            load_lds16(kgk + 32, &Kls[nb][2048 + t * 8]);
            load_lds16(vgk,      &Vls[nb][t * 8]);
            load_lds16(vgk + 32, &Vls[nb][2048 + t * 8]);
        }

        // S = Q K^T : 32 q rows x 64 kv; K-frags shared across q-subtiles
        f32x4 s[2][4];
        __builtin_amdgcn_s_setprio(1);
#pragma unroll
        for (int kt8 = 0; kt8 < 4; ++kt8) {
            bf16x8 k0 = *(const bf16x8*)&Kls[cur][(kt8 * 16 + lrow) * 32 + quad * 8];
            bf16x8 k1 = *(const bf16x8*)&Kls[cur][2048 + (kt8 * 16 + lrow) * 32 + quad * 8];
            s[0][kt8] = mfma_bf16(qf[0][0], k0, z);
            s[0][kt8] = mfma_bf16(qf[0][1], k1, s[0][kt8]);
            s[1][kt8] = mfma_bf16(qf[1][0], k0, z);
            s[1][kt8] = mfma_bf16(qf[1][1], k1, s[1][kt8]);
        }
        __builtin_amdgcn_s_setprio(0);

        // per q-subtile: softmax (log2, defer-max) -> P (swizzled writes)
#pragma unroll
        for (int qb = 0; qb < 2; ++qb) {
            float pm[4];
#pragma unroll
            for (int r = 0; r < 4; ++r)
                pm[r] = fmaxf(fmaxf(s[qb][0][r], s[qb][1][r]),
                              fmaxf(s[qb][2][r], s[qb][3][r]));
            bool ok = (pm[0] <= m_run[qb][0] + 8.f) && (pm[1] <= m_run[qb][1] + 8.f)
                   && (pm[2] <= m_run[qb][2] + 8.f) && (pm[3] <= m_run[qb][3] + 8.f);
            if (!__all(ok)) {
                // rare path: full 16-lane max reduce + rescale
#pragma unroll
                for (int r = 0; r < 4; ++r) {
#pragma unroll
                    for (int off = 1; off < 16; off <<= 1)
                        pm[r] = fmaxf(pm[r], __shfl_xor(pm[r], off, 64));
                    float mnew = fmaxf(m_run[qb][r], pm[r]);
                    float al = exp2_fast(m_run[qb][r] - mnew);
                    m_run[qb][r] = mnew;
                    l_run[qb][r] *= al;
#pragma unroll
                    for (int nt = 0; nt < 4; ++nt) acco[qb][nt][r] *= al;
                }
            }
            // p = exp2(s - m), lane-partial l, P -> swizzled LDS (wave-local)
#pragma unroll
            for (int kt8 = 0; kt8 < 4; ++kt8)
#pragma unroll
                for (int r = 0; r < 4; ++r) {
                    float p = exp2_fast(s[qb][kt8][r] - m_run[qb][r]);
                    l_run[qb][r] += p;
                    int row = quad * 4 + r;
                    int boff = (row * 128 + (kt8 * 16 + lrow) * 2) ^ ((row & 7) << 4);
                    *(unsigned short*)(pb[qb] + boff) = f2bfu(p);
                }
        }

        // PV: V-frags shared across both q-subtiles; swizzled b128 P reads
        __builtin_amdgcn_s_setprio(1);
#pragma unroll
        for (int ks = 0; ks < 2; ++ks) {
            int rb = (lrow * 128 + ks * 64 + quad * 16) ^ ((lrow & 7) << 4);
            bf16x8 pf0 = *(const bf16x8*)(pb[0] + rb);
            bf16x8 pf1 = *(const bf16x8*)(pb[1] + rb);
#pragma unroll
            for (int nt = 0; nt < 4; ++nt) {
                bf16x8 vf = *(const bf16x8*)&Vls[cur][ks * 2048 + (nt * 16 + lrow) * 32 + quad * 8];
                acco[0][nt] = mfma_bf16(pf0, vf, acco[0][nt]);
                acco[1][nt] = mfma_bf16(pf1, vf, acco[1][nt]);
            }
        }
        __builtin_amdgcn_s_setprio(0);

        __syncthreads();   // drains vmcnt(0): next tile staged; buf[cur] free
        cur ^= 1;
    }

    // epilogue: reduce lane-partial l, write normalized O-half + (l, m)
    unsigned short* Ob = Oh + (size_t)kvh * 4096 * 1024;
    float* lmb = lm + (size_t)kvh * 4096 * 16 * 2;
#pragma unroll
    for (int qb = 0; qb < 2; ++qb)
#pragma unroll
        for (int r = 0; r < 4; ++r) {
            float lr = l_run[qb][r];
#pragma unroll
            for (int off = 1; off < 16; off <<= 1)
                lr += __shfl_xor(lr, off, 64);
            float rl = 1.0f / lr;
            int row = b * 2048 + q0 + w * 32 + qb * 16 + quad * 4 + r;
#pragma unroll
            for (int nt = 0; nt < 4; ++nt)
                Ob[(size_t)row * 1024 + h * 64 + nt * 16 + lrow] =
                    f2bfu(acco[qb][nt][r] * rl);
            if (lrow == 0) {
                lmb[((size_t)row * 16 + h) * 2 + 0] = lr;
                lmb[((size_t)row * 16 + h) * 2 + 1] = m_run[qb][r];
            }
        }
}

// ---------------- split-KV merge ----------------
// attn[row][col] = (w0*O0 + w1*O1)/(w0+w1), w_i = l_i * 2^(m_i - m*).
// grid 2048 x 256 threads, 8 elems/thread.
__global__ __launch_bounds__(256) void merge_kernel(
    const unsigned short* __restrict__ Oh, const float* __restrict__ lm,
    unsigned short* __restrict__ attn)
{
    int e = blockIdx.x * 256 + threadIdx.x;
    int base = e * 8;
    int row = base >> 10, col = base & 1023, h = col >> 6;
    const float* lm0 = lm + ((size_t)row * 16 + h) * 2;
    const float* lm1 = lm + ((size_t)(4096 + row) * 16 + h) * 2;
    float l0 = lm0[0], m0 = lm0[1];
    float l1 = lm1[0], m1 = lm1[1];
    float mm = fmaxf(m0, m1);
    float w0 = l0 * exp2_fast(m0 - mm);
    float w1 = l1 * exp2_fast(m1 - mm);
    float rs = 1.0f / (w0 + w1);
    w0 *= rs; w1 *= rs;
    const unsigned short* p0 = Oh + (size_t)row * 1024 + col;
    const unsigned short* p1 = p0 + (size_t)4096 * 1024;
    ushort4 a0 = *(const ushort4*)p0,       a1 = *(const ushort4*)(p0 + 4);
    ushort4 b0 = *(const ushort4*)p1,       b1 = *(const ushort4*)(p1 + 4);
    ushort4 o0, o1;
    o0.x = f2bfu(w0 * bfu2f(a0.x) + w1 * bfu2f(b0.x));
    o0.y = f2bfu(w0 * bfu2f(a0.y) + w1 * bfu2f(b0.y));
    o0.z = f2bfu(w0 * bfu2f(a0.z) + w1 * bfu2f(b0.z));
    o0.w = f2bfu(w0 * bfu2f(a0.w) + w1 * bfu2f(b0.w));
    o1.x = f2bfu(w0 * bfu2f(a1.x) + w1 * bfu2f(b1.x));
    o1.y = f2bfu(w0 * bfu2f(a1.y) + w1 * bfu2f(b1.y));
    o1.z = f2bfu(w0 * bfu2f(a1.z) + w1 * bfu2f(b1.z));
    o1.w = f2bfu(w0 * bfu2f(a1.w) + w1 * bfu2f(b1.w));
    unsigned short* d = attn + (size_t)row * 1024 + col;
    *(ushort4*)d = o0;
    *(ushort4*)(d + 4) = o1;
}

// ---------------- launch ----------------

extern "C" void kernel_launch(void* const* d_in, const int* in_sizes, int n_in,
                              void* d_out, int out_size, void* d_ws, size_t ws_size,
                              hipStream_t stream) {
    const float* x   = (const float*)d_in[0];
    const float* Wq  = (const float*)d_in[1];
    const float* Wkv = (const float*)d_in[2];
    const float* Wk1 = (const float*)d_in[3];
    const float* Wk2 = (const float*)d_in[4];
    const float* Wv1 = (const float*)d_in[5];
    const float* Wv2 = (const float*)d_in[6];
    const float* Wo  = (const float*)d_in[7];
    const float* bo  = (const float*)d_in[8];
    float* out = (float*)d_out;

    unsigned short* p = (unsigned short*)d_ws;
    unsigned short* xb    = p; p += 4194304;   // [4096][1024]
    unsigned short* Wkvb  = p; p += 2097152;   // [1024][2048] bf16
    unsigned short* WqkvT = p; p += 2097152;   // [2048][1024]: WqT*s | WckT | WcvT
    unsigned short* WoT   = p; p += 1048576;   // [1024][1024]
    unsigned short* Wk1T  = p; p += 524288;    // [512][1024]
    unsigned short* Wv1T  = p; p += 524288;    // [512][1024]
    unsigned short* Wk2T  = p; p += 524288;    // [1024][512]
    unsigned short* Wv2T  = p; p += 524288;    // [1024][512]
    unsigned short* qkv2  = p; p += 8388608;   // [4096][2048]  (q | k1 | v1)
    unsigned short* attnb = p; p += 4194304;   // [4096][1024]
    unsigned short* kvo   = p; p += 4194304;   // [4096][1024]  k
    unsigned short* vtb   = p; p += 4194304;   // [32*64][2048]
    unsigned short* Ohb   = p; p += 8388608;   // [2][4096][1024] O halves
    float* lmb = (float*)p; p += 524288;       // [2][4096][16][2] f32 (l,m)

    dim3 blk(256);
    const float qscale = 0.125f * 1.44269504f;  // Dh^-0.5 * log2(e)

    // prep: cvt_x (4096) + cvt_Wkv (2048) + transposes (1024) = 7168 blocks
    prep_kernel<<<7168, blk, 0, stream>>>(
        x, xb, Wkv, Wkvb, Wq, Wo, Wk1, Wv1, Wk2, Wv2,
        WqkvT, WoT, Wk1T, Wv1T, Wk2T, Wv2T, qscale);

    // WckT[512][1024] = Wk1T @ Wkv_k^T ; WcvT = Wv1T @ Wkv_v^T  (z-batched)
    gemm_bf16_kernel<64><<<dim3(16, 4, 2), blk, 0, stream>>>(
        Wk1T, Wv1T, Wkvb, Wkvb + 1024,
        WqkvT + 1024 * 1024, WqkvT + 1536 * 1024,
        1024, 2048, 1024, 1024, nullptr, 0, 0);

    // [q | k1 | v1] = x @ [Wq*s | Wck | Wcv] -> qkv2 [4096][2048]; relu col>=1024
    gemm_bf16_kernel<128><<<dim3(16, 32, 1), blk, 0, stream>>>(
        xb, xb, WqkvT, WqkvT, qkv2, qkv2, 1024, 1024, 2048, 1024, nullptr, 2, 0);

    // k = k1 @ Wk2 -> kvo [4096][1024]; v = v1 @ Wv2 -> TRANSPOSED into vtb
    gemm_bf16_kernel<128, true><<<dim3(8, 32, 2), blk, 0, stream>>>(
        qkv2 + 1024, qkv2 + 1536, Wk2T, Wv2T, kvo, vtb,
        2048, 512, 1024, 512, nullptr, 0, 0);

    // flash split-KV: 1024 blocks (512 tiles x 2 kv halves), 3 blocks/CU
    flash_mfma_kernel<<<dim3(1024), blk, 0, stream>>>(
        qkv2, 2048, kvo, 1024, vtb, Ohb, lmb);
    merge_kernel<<<dim3(2048), blk, 0, stream>>>(Ohb, lmb, attnb);

    // out = attn @ Wo + bo (fp32), BN=64
    gemm_bf16_kernel<64><<<dim3(16, 32, 1), blk, 0, stream>>>(
        attnb, attnb, WoT, WoT, out, out, 1024, 1024, 1024, 1024, bo, 0, 1);
}

// Round 15
// 241.942 us; speedup vs baseline: 1.0358x; 1.0358x over previous
//
#include <hip/hip_runtime.h>
#include <stdint.h>

// MLA bf16-MFMA pipeline R20 (= R16 exactly; consolidation after R17 dbuf,
// R18 BN=64, R19 split-KV all regressed vs R16's 241.1 us):
// B=2, N=2048, D=1024, L=512, H=16, Dh=64.
// GEMM: m97 structure, BK=128 as FOUR [rows][32] sub-chunks, one barrier per
// K-tile (drain amortization: BK 32->64 = -10.6us, 64->128 = -11.1us).
// BN=128 for main/k2v2, BN=64 for out/wGEMM.
// Flash v6: QBLK=128 (4 waves x 32 q rows, 2 q-subtiles), KVBLK=64, K/V LDS
// double-buffered, one barrier/tile, XCD-swizzled grid 512, defer-max THR=8,
// lane-partial l, P [16][64] XOR-swizzle (row&7)<<4.
// Pipeline: reassociated weights (Wck=Wkv_k@Wk1, Wcv=Wkv_v@Wv1), 6 launches:
// prep, wGEMM, mainGEMM(relu col>=1024), k2v2(OUTVT), flash, out.
// SESSION MODEL NOTES (all verified by A/B rounds):
//  - SQ_LDS_BANK_CONFLICT = 4 x ds_read_b128 count (b128 wide-read tax, m134);
//    bit-exact across R5-R19. Not a fixable conflict.
//  - Flash floor ~71-73us: not HBM-bound (XCD swizzle FETCH -5.7x, time flat),
//    not stall-bound (dbuf null R7/R12), not occupancy-bound (split-KV null
//    R19). Per-wave dependency latency at no-pipe->40% is the limiter.
//  - GEMM: dbuf null (R17), BN=64-everywhere regression (R18).

typedef __attribute__((ext_vector_type(8))) __bf16 bf16x8;
typedef __attribute__((ext_vector_type(4))) float f32x4;

__device__ inline unsigned short f2bfu(float f) {
    __bf16 b = (__bf16)f;
    return __builtin_bit_cast(unsigned short, b);
}

__device__ inline float exp2_fast(float f) {
    return __builtin_amdgcn_exp2f(f);   // raw v_exp_f32
}

__device__ inline void load_lds16(const void* g, void* l) {
    __builtin_amdgcn_global_load_lds(
        (const __attribute__((address_space(1))) uint32_t*)g,
        (__attribute__((address_space(3))) uint32_t*)l, 16, 0, 0);
}

__device__ inline f32x4 mfma_bf16(bf16x8 a, bf16x8 b, f32x4 c) {
    return __builtin_amdgcn_mfma_f32_16x16x32_bf16(a, b, c, 0, 0, 0);
}

// ---------------- merged prep kernel ----------------
// blocks [0,4096):      cvt x f32->bf16 (4 elems/thread)
// blocks [4096,6144):   cvt Wkv f32->bf16 (layout kept, [1024][2048])
// blocks [6144,7168):   weight transposes f32 [R][C] -> bf16 [C][R]*sc
__global__ __launch_bounds__(256) void prep_kernel(
    const float* __restrict__ x, unsigned short* __restrict__ xb,
    const float* __restrict__ Wkv, unsigned short* __restrict__ Wkvb,
    const float* __restrict__ Wq,  const float* __restrict__ Wo,
    const float* __restrict__ Wk1, const float* __restrict__ Wv1,
    const float* __restrict__ Wk2, const float* __restrict__ Wv2,
    unsigned short* __restrict__ WqkvT, unsigned short* __restrict__ WoT,
    unsigned short* __restrict__ Wk1T,  unsigned short* __restrict__ Wv1T,
    unsigned short* __restrict__ Wk2T,  unsigned short* __restrict__ Wv2T,
    float qscale)
{
    __shared__ float tile[64][65];
    int id = blockIdx.x;
    int t = threadIdx.x;

    if (id < 6144) {   // ---- elementwise cvt (x, Wkv) ----
        const float* s = (id < 4096) ? x : Wkv;
        unsigned short* d = (id < 4096) ? xb : Wkvb;
        int base = (id < 4096) ? id : (id - 4096);
        int i = (base * 256 + t) * 4;
        float4 v = *(const float4*)&s[i];
        ushort4 o;
        o.x = f2bfu(v.x); o.y = f2bfu(v.y); o.z = f2bfu(v.z); o.w = f2bfu(v.w);
        *(ushort4*)&d[i] = o;
        return;
    }

    // ---- transposes ----
    int r = id - 6144;
    const float* src; unsigned short* dst; int R, C; float sc; int bx, by;
    if (r < 512) {          // Wq / Wo : 16 x 16 x 2
        int z = r >> 8; int rr = r & 255; bx = rr & 15; by = rr >> 4;
        src = z ? Wo : Wq; dst = z ? WoT : WqkvT;
        R = 1024; C = 1024; sc = z ? 1.0f : qscale;
    } else if (r < 768) {   // Wk1 / Wv1 : 8 x 16 x 2
        int rr = r - 512; int z = rr >> 7; rr &= 127; bx = rr & 7; by = rr >> 3;
        src = z ? Wv1 : Wk1; dst = z ? Wv1T : Wk1T;
        R = 1024; C = 512; sc = 1.0f;
    } else {                // Wk2 / Wv2 : 16 x 8 x 2
        int rr = r - 768; int z = rr >> 7; rr &= 127; bx = rr & 15; by = rr >> 4;
        src = z ? Wv2 : Wk2; dst = z ? Wv2T : Wk2T;
        R = 512; C = 1024; sc = 1.0f;
    }

    int c0 = bx * 64, r0 = by * 64;
    int col = t & 63, rr4 = t >> 6;
#pragma unroll
    for (int i = 0; i < 16; ++i)
        tile[rr4 + i * 4][col] = src[(size_t)(r0 + rr4 + i * 4) * C + c0 + col];
    __syncthreads();
#pragma unroll
    for (int i = 0; i < 16; ++i) {
        int r2 = rr4 + i * 4;
        dst[(size_t)(c0 + r2) * R + r0 + col] = f2bfu(tile[col][r2] * sc);
    }
}

// ---------------- bf16 MFMA GEMM (m97 structure, BK=128, BN templated) -----
// C[M][N] = A[M][K] @ Bt[N][K]^T (+bias)(relu). 128xBN tile, BK=128 as four
// [rows][32] sub-chunks. grid (N/BN, M/128, nz), block 256. K % 128 == 0.
// relu: 0=none, 1=all, 2=only columns >= 1024.
// OUTVT: on the z=1 path, write C transposed into C1 as
// vt[(b*1024 + col) * 2048 + (m & 2047)] (b = m >> 11), b64-packed over r.
template<int BN, bool OUTVT = false>
__global__ __launch_bounds__(256) void gemm_bf16_kernel(
    const unsigned short* __restrict__ A0, const unsigned short* __restrict__ A1,
    const unsigned short* __restrict__ B0, const unsigned short* __restrict__ B1,
    void* __restrict__ C0, void* __restrict__ C1,
    int lda, int ldb, int ldc, int K,
    const float* __restrict__ bias, int relu, int out_f32)
{
    const unsigned short* A = blockIdx.z ? A1 : A0;
    const unsigned short* Bt = blockIdx.z ? B1 : B0;
    void* C = blockIdx.z ? C1 : C0;

    constexpr int NI = BN / 32;        // N-frags per wave
    constexpr int AH = 128 * 32;       // halfwords per A sub-chunk
    constexpr int BH = BN * 32;        // halfwords per B sub-chunk
    __shared__ unsigned short Als[4 * AH];
    __shared__ unsigned short Bls[4 * BH];
    int t = threadIdx.x;
    int lane = t & 63, w = t >> 6;
    int n0 = blockIdx.x * BN, m0 = blockIdx.y * 128;
    int wm = (w & 1) * 64, wn = (w >> 1) * (BN / 2);
    int lrow = lane & 15, quad = lane >> 4;

    f32x4 acc[4][NI];
    f32x4 z = {0.f, 0.f, 0.f, 0.f};
#pragma unroll
    for (int i = 0; i < 4; ++i)
#pragma unroll
        for (int j = 0; j < NI; ++j) acc[i][j] = z;

    int c0 = t, c1 = t + 256;
    const unsigned short* ag0 = A + (size_t)(m0 + (c0 >> 2)) * lda + (c0 & 3) * 8;
    const unsigned short* ag1 = A + (size_t)(m0 + (c1 >> 2)) * lda + (c1 & 3) * 8;
    const unsigned short* bg0 = Bt + (size_t)(n0 + (c0 >> 2)) * ldb + (c0 & 3) * 8;
    const unsigned short* bg1 = Bt + (size_t)(n0 + ((c1 >> 2) & (BN - 1))) * ldb + (c1 & 3) * 8;

    for (int k0 = 0; k0 < K; k0 += 128) {
        __syncthreads();
        // four 32-wide sub-chunks, one barrier for all
#pragma unroll
        for (int h = 0; h < 4; ++h) {
            load_lds16(ag0 + k0 + h * 32, &Als[h * AH + c0 * 8]);
            load_lds16(ag1 + k0 + h * 32, &Als[h * AH + c1 * 8]);
            load_lds16(bg0 + k0 + h * 32, &Bls[h * BH + c0 * 8]);
            if constexpr (BN == 128)
                load_lds16(bg1 + k0 + h * 32, &Bls[h * BH + c1 * 8]);
        }
        __syncthreads();

#pragma unroll
        for (int kk = 0; kk < 4; ++kk) {
            bf16x8 af[4], bfr[NI];
#pragma unroll
            for (int mi = 0; mi < 4; ++mi)
                af[mi] = *(const bf16x8*)&Als[kk * AH + (wm + mi * 16 + lrow) * 32 + quad * 8];
#pragma unroll
            for (int ni = 0; ni < NI; ++ni)
                bfr[ni] = *(const bf16x8*)&Bls[kk * BH + (wn + ni * 16 + lrow) * 32 + quad * 8];
#pragma unroll
            for (int mi = 0; mi < 4; ++mi)
#pragma unroll
                for (int ni = 0; ni < NI; ++ni)
                    acc[mi][ni] = mfma_bf16(af[mi], bfr[ni], acc[mi][ni]);
        }
    }

    if (OUTVT && blockIdx.z) {
        // transposed store: vt row = b*1024 + col, col index = n' (seq within batch)
        int bb = m0 >> 11;
        int npb = (m0 & 2047) + wm;
        unsigned short* vt = (unsigned short*)C;
#pragma unroll
        for (int mi = 0; mi < 4; ++mi)
#pragma unroll
            for (int ni = 0; ni < NI; ++ni) {
                int col = n0 + wn + ni * 16 + lrow;
                int np = npb + mi * 16 + quad * 4;
                ushort4 o;
                o.x = f2bfu(acc[mi][ni][0]);
                o.y = f2bfu(acc[mi][ni][1]);
                o.z = f2bfu(acc[mi][ni][2]);
                o.w = f2bfu(acc[mi][ni][3]);
                *(ushort4*)&vt[(size_t)(bb * 1024 + col) * 2048 + np] = o;
            }
        return;
    }

#pragma unroll
    for (int mi = 0; mi < 4; ++mi)
#pragma unroll
        for (int ni = 0; ni < NI; ++ni)
#pragma unroll
            for (int r = 0; r < 4; ++r) {
                int row = m0 + wm + mi * 16 + quad * 4 + r;
                int col = n0 + wn + ni * 16 + lrow;
                float v = acc[mi][ni][r];
                if (bias) v += bias[col];
                if (relu == 1 || (relu == 2 && col >= 1024)) v = fmaxf(v, 0.0f);
                if (out_f32) ((float*)C)[(size_t)row * ldc + col] = v;
                else ((unsigned short*)C)[(size_t)row * ldc + col] = f2bfu(v);
            }
}

// ---------------- MFMA flash attention v6 ----------------
// Q (ldq, scaled by 0.125*log2e), K (ldk): head-interleaved; Vt [32*64][2048].
// grid 512 1D (XCD-swizzled), block 256 (4 waves). Wave w owns Q rows
// w*32..+31 as 2 q-subtiles of 16. KVBLK=64, K/V double-buffered;
// stage(t+1) issued before compute(t); ONE barrier per tile.
// Softmax log2-domain, defer-max THR=8, lane-partial l. P per-wave per-qb
// [16][64] hw, XOR swizzle byte^=(row&7)<<4 on write and read.
__global__ __launch_bounds__(256, 2) void flash_mfma_kernel(
    const unsigned short* __restrict__ Q, int ldq,
    const unsigned short* __restrict__ K, int ldk,
    const unsigned short* __restrict__ Vt, unsigned short* __restrict__ O)
{
    __shared__ __align__(16) unsigned short Kls[2][2 * 64 * 32]; // [buf][half d][64 kv][32 d] 8KB ea
    __shared__ __align__(16) unsigned short Vls[2][2 * 64 * 32]; // [buf][ks][64 d][32 kv]   8KB ea
    __shared__ __align__(16) unsigned short Pls[4][2][16 * 64];  // [wave][qb][16 q][64 kv] swz 16KB

    // XCD swizzle: 512 = 8 XCDs x 64; XCD c gets logical blocks [c*64,(c+1)*64)
    // = 4 consecutive bh (K/V working set < 4MB L2).
    int pbid = blockIdx.x;
    int lbid = (pbid >> 3) + (pbid & 7) * 64;
    int q0 = (lbid & 15) * 128, bh = lbid >> 4;
    int b = bh >> 4, h = bh & 15;
    int t = threadIdx.x;
    int lane = t & 63, w = t >> 6;
    int lrow = lane & 15, quad = lane >> 4;

    // Q fragments: 2 q-subtiles x 2 k-halves (A-layout: row=lrow, k=quad*8)
    bf16x8 qf[2][2];
#pragma unroll
    for (int qb = 0; qb < 2; ++qb) {
        const unsigned short* qrow =
            Q + (size_t)(b * 2048 + q0 + w * 32 + qb * 16 + lrow) * ldq + h * 64;
        qf[qb][0] = *(const bf16x8*)&qrow[quad * 8];
        qf[qb][1] = *(const bf16x8*)&qrow[32 + quad * 8];
    }

    f32x4 z = {0.f, 0.f, 0.f, 0.f};
    f32x4 acco[2][4];
    float m_run[2][4], l_run[2][4];
#pragma unroll
    for (int qb = 0; qb < 2; ++qb)
#pragma unroll
        for (int r = 0; r < 4; ++r) {
            acco[qb][r] = z;
            m_run[qb][r] = -1e30f;
            l_run[qb][r] = 0.f;   // lane-partial sum
        }

    // staging: thread t covers row t>>2 (0..63), segment (t&3)*8
    int row4 = t >> 2;
    int seg = (t & 3) * 8;
    const unsigned short* kg = K + (size_t)(b * 2048 + row4) * ldk + h * 64 + seg;
    const unsigned short* vg = Vt + (size_t)(bh * 64 + row4) * 2048 + seg;

    char* pb[2] = { (char*)&Pls[w][0][0], (char*)&Pls[w][1][0] };

    // prologue: stage tile 0 -> buf 0
    load_lds16(kg,      &Kls[0][t * 8]);
    load_lds16(kg + 32, &Kls[0][2048 + t * 8]);
    load_lds16(vg,      &Vls[0][t * 8]);
    load_lds16(vg + 32, &Vls[0][2048 + t * 8]);
    __syncthreads();

    int cur = 0;
    for (int kt = 0; kt < 2048; kt += 64) {
        // issue next-tile stage into buf cur^1; latency hides under compute
        if (kt + 64 < 2048) {
            const unsigned short* kgk = kg + (size_t)(kt + 64) * ldk;
            const unsigned short* vgk = vg + kt + 64;
            int nb = cur ^ 1;
            load_lds16(kgk,      &Kls[nb][t * 8]);
            load_lds16(kgk + 32, &Kls[nb][2048 + t * 8]);
            load_lds16(vgk,      &Vls[nb][t * 8]);
            load_lds16(vgk + 32, &Vls[nb][2048 + t * 8]);
        }

        // S = Q K^T : 32 q rows x 64 kv; K-frags shared across q-subtiles
        f32x4 s[2][4];
        __builtin_amdgcn_s_setprio(1);
#pragma unroll
        for (int kt8 = 0; kt8 < 4; ++kt8) {
            bf16x8 k0 = *(const bf16x8*)&Kls[cur][(kt8 * 16 + lrow) * 32 + quad * 8];
            bf16x8 k1 = *(const bf16x8*)&Kls[cur][2048 + (kt8 * 16 + lrow) * 32 + quad * 8];
            s[0][kt8] = mfma_bf16(qf[0][0], k0, z);
            s[0][kt8] = mfma_bf16(qf[0][1], k1, s[0][kt8]);
            s[1][kt8] = mfma_bf16(qf[1][0], k0, z);
            s[1][kt8] = mfma_bf16(qf[1][1], k1, s[1][kt8]);
        }
        __builtin_amdgcn_s_setprio(0);

        // per q-subtile: softmax (log2, defer-max) -> P (swizzled writes)
#pragma unroll
        for (int qb = 0; qb < 2; ++qb) {
            float pm[4];
#pragma unroll
            for (int r = 0; r < 4; ++r)
                pm[r] = fmaxf(fmaxf(s[qb][0][r], s[qb][1][r]),
                              fmaxf(s[qb][2][r], s[qb][3][r]));
            bool ok = (pm[0] <= m_run[qb][0] + 8.f) && (pm[1] <= m_run[qb][1] + 8.f)
                   && (pm[2] <= m_run[qb][2] + 8.f) && (pm[3] <= m_run[qb][3] + 8.f);
            if (!__all(ok)) {
                // rare path: full 16-lane max reduce + rescale
#pragma unroll
                for (int r = 0; r < 4; ++r) {
#pragma unroll
                    for (int off = 1; off < 16; off <<= 1)
                        pm[r] = fmaxf(pm[r], __shfl_xor(pm[r], off, 64));
                    float mnew = fmaxf(m_run[qb][r], pm[r]);
                    float al = exp2_fast(m_run[qb][r] - mnew);
                    m_run[qb][r] = mnew;
                    l_run[qb][r] *= al;
#pragma unroll
                    for (int nt = 0; nt < 4; ++nt) acco[qb][nt][r] *= al;
                }
            }
            // p = exp2(s - m), lane-partial l, P -> swizzled LDS (wave-local)
#pragma unroll
            for (int kt8 = 0; kt8 < 4; ++kt8)
#pragma unroll
                for (int r = 0; r < 4; ++r) {
                    float p = exp2_fast(s[qb][kt8][r] - m_run[qb][r]);
                    l_run[qb][r] += p;
                    int row = quad * 4 + r;
                    int boff = (row * 128 + (kt8 * 16 + lrow) * 2) ^ ((row & 7) << 4);
                    *(unsigned short*)(pb[qb] + boff) = f2bfu(p);
                }
        }

        // PV: V-frags shared across both q-subtiles; swizzled b128 P reads
        __builtin_amdgcn_s_setprio(1);
#pragma unroll
        for (int ks = 0; ks < 2; ++ks) {
            int rb = (lrow * 128 + ks * 64 + quad * 16) ^ ((lrow & 7) << 4);
            bf16x8 pf0 = *(const bf16x8*)(pb[0] + rb);
            bf16x8 pf1 = *(const bf16x8*)(pb[1] + rb);
#pragma unroll
            for (int nt = 0; nt < 4; ++nt) {
                bf16x8 vf = *(const bf16x8*)&Vls[cur][ks * 2048 + (nt * 16 + lrow) * 32 + quad * 8];
                acco[0][nt] = mfma_bf16(pf0, vf, acco[0][nt]);
                acco[1][nt] = mfma_bf16(pf1, vf, acco[1][nt]);
            }
        }
        __builtin_amdgcn_s_setprio(0);

        __syncthreads();   // drains vmcnt(0): next tile staged; buf[cur] free
        cur ^= 1;
    }

    // epilogue: reduce lane-partial l across the 16-lane row group, write O
#pragma unroll
    for (int qb = 0; qb < 2; ++qb)
#pragma unroll
        for (int r = 0; r < 4; ++r) {
            float lr = l_run[qb][r];
#pragma unroll
            for (int off = 1; off < 16; off <<= 1)
                lr += __shfl_xor(lr, off, 64);
            float rl = 1.0f / lr;
            int row = b * 2048 + q0 + w * 32 + qb * 16 + quad * 4 + r;
#pragma unroll
            for (int nt = 0; nt < 4; ++nt)
                O[(size_t)row * 1024 + h * 64 + nt * 16 + lrow] =
                    f2bfu(acco[qb][nt][r] * rl);
        }
}

// ---------------- launch ----------------

extern "C" void kernel_launch(void* const* d_in, const int* in_sizes, int n_in,
                              void* d_out, int out_size, void* d_ws, size_t ws_size,
                              hipStream_t stream) {
    const float* x   = (const float*)d_in[0];
    const float* Wq  = (const float*)d_in[1];
    const float* Wkv = (const float*)d_in[2];
    const float* Wk1 = (const float*)d_in[3];
    const float* Wk2 = (const float*)d_in[4];
    const float* Wv1 = (const float*)d_in[5];
    const float* Wv2 = (const float*)d_in[6];
    const float* Wo  = (const float*)d_in[7];
    const float* bo  = (const float*)d_in[8];
    float* out = (float*)d_out;

    unsigned short* p = (unsigned short*)d_ws;
    unsigned short* xb    = p; p += 4194304;   // [4096][1024]
    unsigned short* Wkvb  = p; p += 2097152;   // [1024][2048] bf16, layout kept
    unsigned short* WqkvT = p; p += 2097152;   // [2048][1024]: WqT*s | WckT | WcvT
    unsigned short* WoT   = p; p += 1048576;   // [1024][1024]
    unsigned short* Wk1T  = p; p += 524288;    // [512][1024]
    unsigned short* Wv1T  = p; p += 524288;    // [512][1024]
    unsigned short* Wk2T  = p; p += 524288;    // [1024][512]
    unsigned short* Wv2T  = p; p += 524288;    // [1024][512]
    unsigned short* qkv2  = p; p += 8388608;   // [4096][2048]  (q | k1 | v1)
    unsigned short* attnb = p; p += 4194304;   // [4096][1024]
    unsigned short* kvo   = p; p += 4194304;   // [4096][1024]  k
    unsigned short* vtb   = p; p += 4194304;   // [32*64][2048]

    dim3 blk(256);
    const float qscale = 0.125f * 1.44269504f;  // Dh^-0.5 * log2(e)

    // prep: cvt_x (4096) + cvt_Wkv (2048) + transposes (1024) = 7168 blocks
    prep_kernel<<<7168, blk, 0, stream>>>(
        x, xb, Wkv, Wkvb, Wq, Wo, Wk1, Wv1, Wk2, Wv2,
        WqkvT, WoT, Wk1T, Wv1T, Wk2T, Wv2T, qscale);

    // WckT[512][1024] = Wk1T @ Wkv_k^T ; WcvT = Wv1T @ Wkv_v^T  (z-batched)
    gemm_bf16_kernel<64><<<dim3(16, 4, 2), blk, 0, stream>>>(
        Wk1T, Wv1T, Wkvb, Wkvb + 1024,
        WqkvT + 1024 * 1024, WqkvT + 1536 * 1024,
        1024, 2048, 1024, 1024, nullptr, 0, 0);

    // [q | k1 | v1] = x @ [Wq*s | Wck | Wcv] -> qkv2 [4096][2048]; relu col>=1024
    gemm_bf16_kernel<128><<<dim3(16, 32, 1), blk, 0, stream>>>(
        xb, xb, WqkvT, WqkvT, qkv2, qkv2, 1024, 1024, 2048, 1024, nullptr, 2, 0);

    // k = k1 @ Wk2 -> kvo [4096][1024]; v = v1 @ Wv2 -> TRANSPOSED into vtb
    gemm_bf16_kernel<128, true><<<dim3(8, 32, 2), blk, 0, stream>>>(
        qkv2 + 1024, qkv2 + 1536, Wk2T, Wv2T, kvo, vtb,
        2048, 512, 1024, 512, nullptr, 0, 0);

    flash_mfma_kernel<<<dim3(512), blk, 0, stream>>>(qkv2, 2048, kvo, 1024, vtb, attnb);

    // out = attn @ Wo + bo (fp32), BN=64
    gemm_bf16_kernel<64><<<dim3(16, 32, 1), blk, 0, stream>>>(
        attnb, attnb, WoT, WoT, out, out, 1024, 1024, 1024, 1024, bo, 0, 1);
}